// Round 4
// baseline (627.010 us; speedup 1.0000x reference)
//
#include <hip/hip_runtime.h>
#include <hip/hip_bf16.h>
#include <math.h>

#define N_HEADN 100000
#define N_TAILN 100000
#define NEDGE   1600000
#define SLOPE   0.2f

static __device__ __forceinline__ float bf2f(__hip_bfloat16 x) { return __bfloat162float(x); }

// ---------------- k0: wl[128][4], wr[128][4], he[8][4]  (all fp32 in) ----------------
__global__ void k0_prep(const float* __restrict__ W,
                        const float* __restrict__ W_e,
                        const float* __restrict__ a_l,
                        const float* __restrict__ a_r,
                        const float* __restrict__ a_e,
                        const float* __restrict__ emb,
                        float* __restrict__ wl, float* __restrict__ wr,
                        float* __restrict__ he) {
  const int t = threadIdx.x;  // 128 threads
  #pragma unroll
  for (int h = 0; h < 4; ++h) {
    float sl = 0.f, sr = 0.f;
    for (int d = 0; d < 32; ++d) {
      const float w = W[t * 128 + h * 32 + d];
      sl += w * a_l[h * 32 + d];
      sr += w * a_r[h * 32 + d];
    }
    wl[t * 4 + h] = sl;
    wr[t * 4 + h] = sr;
  }
  if (t < 32) {
    const int et = t >> 2, h = t & 3;
    float acc = 0.f;
    for (int d = 0; d < 32; ++d) {
      float tmp = 0.f;
      for (int f = 0; f < 32; ++f)
        tmp += emb[et * 32 + f] * W_e[f * 128 + h * 32 + d];
      acc += a_e[h * 32 + d] * tmp;
    }
    he[et * 4 + h] = acc;
  }
}

// ---------------- k1: h_l / h_r = feat @ wvec  (wave per node, fp32 feat) ----------------
__global__ __launch_bounds__(256) void k1_hlr(const float* __restrict__ feat,
                                              const float* __restrict__ wv,
                                              float* __restrict__ o, int n) {
  const int gid = blockIdx.x * 256 + threadIdx.x;
  const int node = gid >> 6, lane = gid & 63;
  if (node >= n) return;
  const float* row = feat + (size_t)node * 128;
  const float x0 = row[lane];
  const float x1 = row[lane + 64];
  const float4 w0 = *(const float4*)(wv + lane * 4);
  const float4 w1 = *(const float4*)(wv + (lane + 64) * 4);
  float p0 = x0 * w0.x + x1 * w1.x;
  float p1 = x0 * w0.y + x1 * w1.y;
  float p2 = x0 * w0.z + x1 * w1.z;
  float p3 = x0 * w0.w + x1 * w1.w;
  #pragma unroll
  for (int m = 32; m; m >>= 1) {
    p0 += __shfl_xor(p0, m, 64);
    p1 += __shfl_xor(p1, m, 64);
    p2 += __shfl_xor(p2, m, 64);
    p3 += __shfl_xor(p3, m, 64);
  }
  if (lane == 0) *(float4*)(o + (size_t)node * 4) = make_float4(p0, p1, p2, p3);
}

// ---------------- k2: h_tail = tail @ W  (fp32 in, bf16 out, fp32 accumulate) ----------------
__global__ __launch_bounds__(256) void k2_gemm(const float* __restrict__ A,
                                               const float* __restrict__ W,
                                               __hip_bfloat16* __restrict__ out) {
  __shared__ float sW[128 * 128];                    // 64 KB
  __shared__ __align__(16) float sA[8 * 128];        // 4 KB
  const int t = threadIdx.x;
  for (int i = t; i < 128 * 128; i += 256) sW[i] = W[i];
  const size_t r0 = (size_t)blockIdx.x * 8;
  for (int i = t; i < 8 * 128; i += 256) sA[i] = A[r0 * 128 + i];
  __syncthreads();
  const int c = t & 127, rb = t >> 7;                // rb in {0,1}
  float acc0 = 0.f, acc1 = 0.f, acc2 = 0.f, acc3 = 0.f;
  for (int k = 0; k < 128; k += 4) {
    const float w0 = sW[(k + 0) * 128 + c];
    const float w1 = sW[(k + 1) * 128 + c];
    const float w2 = sW[(k + 2) * 128 + c];
    const float w3 = sW[(k + 3) * 128 + c];
    const float4 a0 = *(const float4*)&sA[(rb + 0) * 128 + k];
    const float4 a1 = *(const float4*)&sA[(rb + 2) * 128 + k];
    const float4 a2 = *(const float4*)&sA[(rb + 4) * 128 + k];
    const float4 a3 = *(const float4*)&sA[(rb + 6) * 128 + k];
    acc0 += a0.x * w0 + a0.y * w1 + a0.z * w2 + a0.w * w3;
    acc1 += a1.x * w0 + a1.y * w1 + a1.z * w2 + a1.w * w3;
    acc2 += a2.x * w0 + a2.y * w1 + a2.z * w2 + a2.w * w3;
    acc3 += a3.x * w0 + a3.y * w1 + a3.z * w2 + a3.w * w3;
  }
  out[(r0 + rb + 0) * 128 + c] = __float2bfloat16(acc0);
  out[(r0 + rb + 2) * 128 + c] = __float2bfloat16(acc1);
  out[(r0 + rb + 4) * 128 + c] = __float2bfloat16(acc2);
  out[(r0 + rb + 6) * 128 + c] = __float2bfloat16(acc3);
}

// ---------------- CSR build ----------------
__global__ __launch_bounds__(256) void k3_count(const int* __restrict__ head_ind,
                                                int* __restrict__ deg) {
  const int e = blockIdx.x * 256 + threadIdx.x;   // E divisible by 256
  atomicAdd(&deg[head_ind[e]], 1);
}

__global__ __launch_bounds__(256) void scan1(const int* __restrict__ deg, int* __restrict__ bsum) {
  __shared__ int sm[256];
  const int i = blockIdx.x * 256 + threadIdx.x;
  sm[threadIdx.x] = (i < N_HEADN) ? deg[i] : 0;
  __syncthreads();
  for (int st = 128; st > 0; st >>= 1) {
    if (threadIdx.x < st) sm[threadIdx.x] += sm[threadIdx.x + st];
    __syncthreads();
  }
  if (threadIdx.x == 0) bsum[blockIdx.x] = sm[0];
}

__global__ __launch_bounds__(512) void scan2(int* __restrict__ bsum, int nb) {
  __shared__ int sm[512];
  const int t = threadIdx.x;
  const int v = (t < nb) ? bsum[t] : 0;
  sm[t] = v;
  __syncthreads();
  for (int st = 1; st < 512; st <<= 1) {
    const int add = (t >= st) ? sm[t - st] : 0;
    __syncthreads();
    sm[t] += add;
    __syncthreads();
  }
  if (t < nb) bsum[t] = sm[t] - v;  // exclusive
}

// cursor aliases deg: each thread reads deg[i] before any write; no cross-block RAW.
__global__ __launch_bounds__(256) void scan3(const int* __restrict__ deg,
                                             const int* __restrict__ bsum,
                                             int* __restrict__ off, int* __restrict__ cursor) {
  __shared__ int sm[256];
  const int i = blockIdx.x * 256 + threadIdx.x;
  const int v = (i < N_HEADN) ? deg[i] : 0;
  sm[threadIdx.x] = v;
  __syncthreads();
  for (int st = 1; st < 256; st <<= 1) {
    const int add = (threadIdx.x >= st) ? sm[threadIdx.x - st] : 0;
    __syncthreads();
    sm[threadIdx.x] += add;
    __syncthreads();
  }
  const int excl = sm[threadIdx.x] - v + bsum[blockIdx.x];
  if (i < N_HEADN) { off[i] = excl; cursor[i] = excl; }
  if (i == N_HEADN - 1) off[N_HEADN] = excl + v;
}

// pt slot = ti | (etype << 17)   (ti < 2^17, etype < 8)
__global__ __launch_bounds__(256) void k3_scatter(const int* __restrict__ head_ind,
                                                  const int* __restrict__ tail_ind,
                                                  const int* __restrict__ etype,
                                                  int* __restrict__ cursor,
                                                  int* __restrict__ pt) {
  const int e = blockIdx.x * 256 + threadIdx.x;
  const int hi = head_ind[e];
  const int ppos = atomicAdd(&cursor[hi], 1);
  pt[ppos] = tail_ind[e] | (etype[e] << 17);
}

// ---------------- k4: per-node online softmax + aggregation (fp32 out) ----------------
__global__ __launch_bounds__(256) void k4_agg(const int* __restrict__ off,
                                              const int* __restrict__ pt,
                                              const float* __restrict__ h_l,
                                              const float* __restrict__ h_r,
                                              const float* __restrict__ he,
                                              const __hip_bfloat16* __restrict__ h_tail,
                                              float* __restrict__ out) {
  __shared__ __align__(16) float sw[4][64][4];
  __shared__ int sti[4][64];
  __shared__ int schk[4];
  __shared__ float she[32];
  const int wid = threadIdx.x >> 6;
  const int lane = threadIdx.x & 63;
  if (threadIdx.x < 32) she[threadIdx.x] = he[threadIdx.x];
  const int n = blockIdx.x * 4 + wid;               // grid exact: 25000*4
  const int s = off[n], e = off[n + 1];
  const int nch = (e - s + 63) >> 6;
  if (lane == 0) schk[wid] = nch;
  __syncthreads();
  const int cmax = max(max(schk[0], schk[1]), max(schk[2], schk[3]));
  const float4 hl = *(const float4*)(h_l + (size_t)n * 4);
  const int h = lane >> 4;                          // head owning dims 2*lane, 2*lane+1
  float m0 = -1e30f, m1 = -1e30f, m2 = -1e30f, m3 = -1e30f;
  float s0 = 0.f, s1 = 0.f, s2 = 0.f, s3 = 0.f;
  float ax = 0.f, ay = 0.f;
  for (int c = 0; c < cmax; ++c) {
    const bool act = (c < nch);
    const int base = s + (c << 6);
    int rem = 0;
    if (act) {
      rem = min(64, e - base);
      float a0 = -1e30f, a1 = -1e30f, a2 = -1e30f, a3 = -1e30f;
      if (lane < rem) {
        const int pk = pt[base + lane];
        const int ti = pk & 0x1FFFF;
        const int et = pk >> 17;
        const float4 hr = *(const float4*)(h_r + (size_t)ti * 4);
        a0 = hl.x + hr.x + she[et * 4 + 0];
        a1 = hl.y + hr.y + she[et * 4 + 1];
        a2 = hl.z + hr.z + she[et * 4 + 2];
        a3 = hl.w + hr.w + she[et * 4 + 3];
        a0 = a0 > 0.f ? a0 : SLOPE * a0;
        a1 = a1 > 0.f ? a1 : SLOPE * a1;
        a2 = a2 > 0.f ? a2 : SLOPE * a2;
        a3 = a3 > 0.f ? a3 : SLOPE * a3;
        sti[wid][lane] = ti;
      }
      float c0 = a0, c1 = a1, c2 = a2, c3 = a3;
      #pragma unroll
      for (int msk = 32; msk; msk >>= 1) {
        c0 = fmaxf(c0, __shfl_xor(c0, msk, 64));
        c1 = fmaxf(c1, __shfl_xor(c1, msk, 64));
        c2 = fmaxf(c2, __shfl_xor(c2, msk, 64));
        c3 = fmaxf(c3, __shfl_xor(c3, msk, 64));
      }
      const float nm0 = fmaxf(m0, c0), nm1 = fmaxf(m1, c1);
      const float nm2 = fmaxf(m2, c2), nm3 = fmaxf(m3, c3);
      const float e0 = __expf(m0 - nm0), e1 = __expf(m1 - nm1);
      const float e2 = __expf(m2 - nm2), e3 = __expf(m3 - nm3);
      const float w0 = __expf(a0 - nm0), w1 = __expf(a1 - nm1);
      const float w2 = __expf(a2 - nm2), w3 = __expf(a3 - nm3);
      float t0 = w0, t1 = w1, t2 = w2, t3 = w3;
      #pragma unroll
      for (int msk = 32; msk; msk >>= 1) {
        t0 += __shfl_xor(t0, msk, 64);
        t1 += __shfl_xor(t1, msk, 64);
        t2 += __shfl_xor(t2, msk, 64);
        t3 += __shfl_xor(t3, msk, 64);
      }
      s0 = s0 * e0 + t0; s1 = s1 * e1 + t1;
      s2 = s2 * e2 + t2; s3 = s3 * e3 + t3;
      m0 = nm0; m1 = nm1; m2 = nm2; m3 = nm3;
      *(float4*)&sw[wid][lane][0] = make_float4(w0, w1, w2, w3);
      const float sc = (h == 0) ? e0 : (h == 1) ? e1 : (h == 2) ? e2 : e3;
      ax *= sc; ay *= sc;
    }
    __syncthreads();
    if (act) {
      const __hip_bfloat162* __restrict__ ht = (const __hip_bfloat162*)h_tail + lane;
      for (int j = 0; j < rem; ++j) {
        const float wj = sw[wid][j][h];
        const int ti = sti[wid][j];
        const __hip_bfloat162 v = ht[(size_t)ti * 64];
        ax += wj * bf2f(v.x);
        ay += wj * bf2f(v.y);
      }
    }
    __syncthreads();
  }
  const float denom = (h == 0) ? s0 : (h == 1) ? s1 : (h == 2) ? s2 : s3;
  const float inv = denom > 0.f ? 1.f / denom : 0.f;
  float ox = ax * inv, oy = ay * inv;
  ox = ox > 0.f ? ox : expm1f(ox);
  oy = oy > 0.f ? oy : expm1f(oy);
  *(float2*)(out + (size_t)n * 128 + 2 * lane) = make_float2(ox, oy);
}

extern "C" void kernel_launch(void* const* d_in, const int* in_sizes, int n_in,
                              void* d_out, int out_size, void* d_ws, size_t ws_size,
                              hipStream_t stream) {
  const float* head = (const float*)d_in[0];
  const float* tail = (const float*)d_in[1];
  const int* elist  = (const int*)d_in[2];
  const int* etype  = (const int*)d_in[3];
  const float* W    = (const float*)d_in[4];
  const float* W_e  = (const float*)d_in[5];
  const float* a_l  = (const float*)d_in[6];
  const float* a_r  = (const float*)d_in[7];
  const float* a_e  = (const float*)d_in[8];
  const float* emb  = (const float*)d_in[9];
  const int* head_ind = elist;
  const int* tail_ind = elist + NEDGE;
  (void)in_sizes; (void)n_in; (void)out_size; (void)ws_size;

  char* p = (char*)d_ws;
  size_t o = 0;
  auto carve = [&](size_t bytes) {
    char* r = p + o;
    o += (bytes + 255) & ~(size_t)255;
    return r;
  };
  // total ~36.0 MB
  __hip_bfloat16* h_tail = (__hip_bfloat16*)carve((size_t)N_TAILN * 128 * 2);  // 25.6 MB
  int*   pt     = (int*)   carve((size_t)NEDGE * 4);                            // 6.4 MB
  float* h_l    = (float*) carve((size_t)N_HEADN * 4 * 4);                      // 1.6 MB
  float* h_r    = (float*) carve((size_t)N_TAILN * 4 * 4);                      // 1.6 MB
  int*   deg    = (int*)   carve((size_t)N_HEADN * 4);                          // 0.4 MB
  int*   off    = (int*)   carve((size_t)(N_HEADN + 1) * 4);                    // 0.4 MB
  int*   cursor = deg;                                                          // alias (safe, see scan3)
  int*   bsum   = (int*)   carve(512 * 4);
  float* wl     = (float*) carve(128 * 4 * 4);
  float* wr     = (float*) carve(128 * 4 * 4);
  float* he     = (float*) carve(8 * 4 * 4);

  hipMemsetAsync(deg, 0, N_HEADN * sizeof(int), stream);
  k0_prep<<<1, 128, 0, stream>>>(W, W_e, a_l, a_r, a_e, emb, wl, wr, he);
  k1_hlr<<<(N_HEADN * 64) / 256, 256, 0, stream>>>(head, wl, h_l, N_HEADN);
  k1_hlr<<<(N_TAILN * 64) / 256, 256, 0, stream>>>(tail, wr, h_r, N_TAILN);
  k2_gemm<<<N_TAILN / 8, 256, 0, stream>>>(tail, W, h_tail);
  k3_count<<<NEDGE / 256, 256, 0, stream>>>(head_ind, deg);
  const int nb = (N_HEADN + 255) / 256;  // 391
  scan1<<<nb, 256, 0, stream>>>(deg, bsum);
  scan2<<<1, 512, 0, stream>>>(bsum, nb);
  scan3<<<nb, 256, 0, stream>>>(deg, bsum, off, cursor);
  k3_scatter<<<NEDGE / 256, 256, 0, stream>>>(head_ind, tail_ind, etype, cursor, pt);
  k4_agg<<<N_HEADN / 4, 256, 0, stream>>>(off, pt, h_l, h_r, he, h_tail, (float*)d_out);
}

// Round 5
// 545.931 us; speedup vs baseline: 1.1485x; 1.1485x over previous
//
#include <hip/hip_runtime.h>
#include <hip/hip_bf16.h>
#include <math.h>

#define N_HEADN 100000
#define N_TAILN 100000
#define NEDGE   1600000
#define SLOPE   0.2f

static __device__ __forceinline__ float bf2f(__hip_bfloat16 x) { return __bfloat162float(x); }

// ---------------- k0: wl[128][4], wr[128][4], he[8][4]  (all fp32 in) ----------------
__global__ void k0_prep(const float* __restrict__ W,
                        const float* __restrict__ W_e,
                        const float* __restrict__ a_l,
                        const float* __restrict__ a_r,
                        const float* __restrict__ a_e,
                        const float* __restrict__ emb,
                        float* __restrict__ wl, float* __restrict__ wr,
                        float* __restrict__ he) {
  const int t = threadIdx.x;  // 128 threads
  #pragma unroll
  for (int h = 0; h < 4; ++h) {
    float sl = 0.f, sr = 0.f;
    for (int d = 0; d < 32; ++d) {
      const float w = W[t * 128 + h * 32 + d];
      sl += w * a_l[h * 32 + d];
      sr += w * a_r[h * 32 + d];
    }
    wl[t * 4 + h] = sl;
    wr[t * 4 + h] = sr;
  }
  if (t < 32) {
    const int et = t >> 2, h = t & 3;
    float acc = 0.f;
    for (int d = 0; d < 32; ++d) {
      float tmp = 0.f;
      for (int f = 0; f < 32; ++f)
        tmp += emb[et * 32 + f] * W_e[f * 128 + h * 32 + d];
      acc += a_e[h * 32 + d] * tmp;
    }
    he[et * 4 + h] = acc;
  }
}

// ---------------- k1: h_l = head @ wl  (wave per node) ----------------
__global__ __launch_bounds__(256) void k1_hlr(const float* __restrict__ feat,
                                              const float* __restrict__ wv,
                                              float* __restrict__ o, int n) {
  const int gid = blockIdx.x * 256 + threadIdx.x;
  const int node = gid >> 6, lane = gid & 63;
  if (node >= n) return;
  const float* row = feat + (size_t)node * 128;
  const float x0 = row[lane];
  const float x1 = row[lane + 64];
  const float4 w0 = *(const float4*)(wv + lane * 4);
  const float4 w1 = *(const float4*)(wv + (lane + 64) * 4);
  float p0 = x0 * w0.x + x1 * w1.x;
  float p1 = x0 * w0.y + x1 * w1.y;
  float p2 = x0 * w0.z + x1 * w1.z;
  float p3 = x0 * w0.w + x1 * w1.w;
  #pragma unroll
  for (int m = 32; m; m >>= 1) {
    p0 += __shfl_xor(p0, m, 64);
    p1 += __shfl_xor(p1, m, 64);
    p2 += __shfl_xor(p2, m, 64);
    p3 += __shfl_xor(p3, m, 64);
  }
  if (lane == 0) *(float4*)(o + (size_t)node * 4) = make_float4(p0, p1, p2, p3);
}

// ---------------- k2: h_tail = tail @ W (bf16 out) + fused h_r = tail @ wr ----------------
// 64 rows/block; W staged bf16 [k][c] (32 KB); A staged fp32 transposed [k][r] pad 68 (34.8 KB).
// Thread tile 4 rows x 8 cols: per k, 2x ds_read_b128 feed 32 FMAs.
__global__ __launch_bounds__(256) void k2_gemm(const float* __restrict__ A,
                                               const float* __restrict__ W,
                                               const float* __restrict__ wr,
                                               __hip_bfloat16* __restrict__ out,
                                               float* __restrict__ h_r) {
  __shared__ __hip_bfloat16 sW[128 * 128];        // [k][c]  32 KB
  __shared__ __align__(16) float sA[128 * 68];    // [k][r]  34.8 KB (pad 64->68: 16B-aligned, conflict-free)
  __shared__ float swr[512];                      // wr[k][h] 2 KB
  const int t = threadIdx.x;
  for (int i = t; i < 128 * 128; i += 256) sW[i] = __float2bfloat16(W[i]);
  for (int i = t; i < 512; i += 256) swr[i] = wr[i];
  const int r0 = blockIdx.x * 64;
  for (int i = t; i < 64 * 128; i += 256) {
    const int r = i >> 7, k = i & 127;
    sA[k * 68 + r] = (r0 + r < N_TAILN) ? A[(size_t)(r0 + r) * 128 + k] : 0.f;
  }
  __syncthreads();

  // fused h_r: thread t -> (row t>>2, head t&3); sA reads broadcast within 4-lane groups
  {
    const int r = t >> 2, hh = t & 3;
    float accr = 0.f;
    for (int k = 0; k < 128; ++k)
      accr += sA[k * 68 + r] * swr[k * 4 + hh];
    if (r0 + r < N_TAILN) h_r[(size_t)(r0 + r) * 4 + hh] = accr;
  }

  // main GEMM
  const int tc = t & 15, tr = t >> 4;
  const int c8 = tc * 8, r4 = tr * 4;
  float acc[4][8];
  #pragma unroll
  for (int i = 0; i < 4; ++i)
    #pragma unroll
    for (int j = 0; j < 8; ++j) acc[i][j] = 0.f;
  #pragma unroll 2
  for (int k = 0; k < 128; ++k) {
    const uint4 wb = *(const uint4*)&sW[k * 128 + c8];
    float w[8];
    w[0] = __uint_as_float(wb.x << 16); w[1] = __uint_as_float(wb.x & 0xffff0000u);
    w[2] = __uint_as_float(wb.y << 16); w[3] = __uint_as_float(wb.y & 0xffff0000u);
    w[4] = __uint_as_float(wb.z << 16); w[5] = __uint_as_float(wb.z & 0xffff0000u);
    w[6] = __uint_as_float(wb.w << 16); w[7] = __uint_as_float(wb.w & 0xffff0000u);
    const float4 av = *(const float4*)&sA[k * 68 + r4];
    const float ar[4] = {av.x, av.y, av.z, av.w};
    #pragma unroll
    for (int i = 0; i < 4; ++i)
      #pragma unroll
      for (int j = 0; j < 8; ++j)
        acc[i][j] += ar[i] * w[j];
  }
  #pragma unroll
  for (int i = 0; i < 4; ++i) {
    const int rr = r0 + r4 + i;
    if (rr < N_TAILN) {
      union { unsigned short us[8]; uint4 u4; } pk;
      #pragma unroll
      for (int j = 0; j < 8; ++j) {
        __hip_bfloat16 b = __float2bfloat16(acc[i][j]);
        pk.us[j] = *(unsigned short*)&b;
      }
      *(uint4*)&out[(size_t)rr * 128 + c8] = pk.u4;
    }
  }
}

// ---------------- CSR build ----------------
__global__ __launch_bounds__(256) void k3_count(const int* __restrict__ head_ind,
                                                int* __restrict__ deg) {
  const int e = blockIdx.x * 256 + threadIdx.x;
  atomicAdd(&deg[head_ind[e]], 1);
}

__global__ __launch_bounds__(256) void scan1(const int* __restrict__ deg, int* __restrict__ bsum) {
  __shared__ int sm[256];
  const int i = blockIdx.x * 256 + threadIdx.x;
  sm[threadIdx.x] = (i < N_HEADN) ? deg[i] : 0;
  __syncthreads();
  for (int st = 128; st > 0; st >>= 1) {
    if (threadIdx.x < st) sm[threadIdx.x] += sm[threadIdx.x + st];
    __syncthreads();
  }
  if (threadIdx.x == 0) bsum[blockIdx.x] = sm[0];
}

__global__ __launch_bounds__(512) void scan2(int* __restrict__ bsum, int nb) {
  __shared__ int sm[512];
  const int t = threadIdx.x;
  const int v = (t < nb) ? bsum[t] : 0;
  sm[t] = v;
  __syncthreads();
  for (int st = 1; st < 512; st <<= 1) {
    const int add = (t >= st) ? sm[t - st] : 0;
    __syncthreads();
    sm[t] += add;
    __syncthreads();
  }
  if (t < nb) bsum[t] = sm[t] - v;  // exclusive
}

// cursor aliases deg: each thread reads deg[i] before writing cursor[i].
__global__ __launch_bounds__(256) void scan3(const int* __restrict__ deg,
                                             const int* __restrict__ bsum,
                                             int* __restrict__ off, int* __restrict__ cursor) {
  __shared__ int sm[256];
  const int i = blockIdx.x * 256 + threadIdx.x;
  const int v = (i < N_HEADN) ? deg[i] : 0;
  sm[threadIdx.x] = v;
  __syncthreads();
  for (int st = 1; st < 256; st <<= 1) {
    const int add = (threadIdx.x >= st) ? sm[threadIdx.x - st] : 0;
    __syncthreads();
    sm[threadIdx.x] += add;
    __syncthreads();
  }
  const int excl = sm[threadIdx.x] - v + bsum[blockIdx.x];
  if (i < N_HEADN) { off[i] = excl; cursor[i] = excl; }
  if (i == N_HEADN - 1) off[N_HEADN] = excl + v;
}

// pt slot = ti | (etype << 17)   (ti < 2^17, etype < 8)
__global__ __launch_bounds__(256) void k3_scatter(const int* __restrict__ head_ind,
                                                  const int* __restrict__ tail_ind,
                                                  const int* __restrict__ etype,
                                                  int* __restrict__ cursor,
                                                  int* __restrict__ pt) {
  const int e = blockIdx.x * 256 + threadIdx.x;
  const int hi = head_ind[e];
  const int ppos = atomicAdd(&cursor[hi], 1);
  pt[ppos] = tail_ind[e] | (etype[e] << 17);
}

// ---------------- k4: per-node online softmax + aggregation (fp32 out) ----------------
__global__ __launch_bounds__(256) void k4_agg(const int* __restrict__ off,
                                              const int* __restrict__ pt,
                                              const float* __restrict__ h_l,
                                              const float* __restrict__ h_r,
                                              const float* __restrict__ he,
                                              const __hip_bfloat16* __restrict__ h_tail,
                                              float* __restrict__ out) {
  __shared__ __align__(16) float sw[4][64][4];
  __shared__ int sti[4][64];
  __shared__ int schk[4];
  __shared__ float she[32];
  const int wid = threadIdx.x >> 6;
  const int lane = threadIdx.x & 63;
  if (threadIdx.x < 32) she[threadIdx.x] = he[threadIdx.x];
  const int n = blockIdx.x * 4 + wid;               // grid exact: 25000*4
  const int s = off[n], e = off[n + 1];
  const int nch = (e - s + 63) >> 6;
  if (lane == 0) schk[wid] = nch;
  __syncthreads();
  const int cmax = max(max(schk[0], schk[1]), max(schk[2], schk[3]));
  const float4 hl = *(const float4*)(h_l + (size_t)n * 4);
  const int h = lane >> 4;                          // head owning dims 2*lane, 2*lane+1
  float m0 = -1e30f, m1 = -1e30f, m2 = -1e30f, m3 = -1e30f;
  float s0 = 0.f, s1 = 0.f, s2 = 0.f, s3 = 0.f;
  float ax = 0.f, ay = 0.f;
  for (int c = 0; c < cmax; ++c) {
    const bool act = (c < nch);
    const int base = s + (c << 6);
    int rem = 0;
    if (act) {
      rem = min(64, e - base);
      float a0 = -1e30f, a1 = -1e30f, a2 = -1e30f, a3 = -1e30f;
      if (lane < rem) {
        const int pk = pt[base + lane];
        const int ti = pk & 0x1FFFF;
        const int et = pk >> 17;
        const float4 hr = *(const float4*)(h_r + (size_t)ti * 4);
        a0 = hl.x + hr.x + she[et * 4 + 0];
        a1 = hl.y + hr.y + she[et * 4 + 1];
        a2 = hl.z + hr.z + she[et * 4 + 2];
        a3 = hl.w + hr.w + she[et * 4 + 3];
        a0 = a0 > 0.f ? a0 : SLOPE * a0;
        a1 = a1 > 0.f ? a1 : SLOPE * a1;
        a2 = a2 > 0.f ? a2 : SLOPE * a2;
        a3 = a3 > 0.f ? a3 : SLOPE * a3;
        sti[wid][lane] = ti;
      }
      float c0 = a0, c1 = a1, c2 = a2, c3 = a3;
      #pragma unroll
      for (int msk = 32; msk; msk >>= 1) {
        c0 = fmaxf(c0, __shfl_xor(c0, msk, 64));
        c1 = fmaxf(c1, __shfl_xor(c1, msk, 64));
        c2 = fmaxf(c2, __shfl_xor(c2, msk, 64));
        c3 = fmaxf(c3, __shfl_xor(c3, msk, 64));
      }
      const float nm0 = fmaxf(m0, c0), nm1 = fmaxf(m1, c1);
      const float nm2 = fmaxf(m2, c2), nm3 = fmaxf(m3, c3);
      const float e0 = __expf(m0 - nm0), e1 = __expf(m1 - nm1);
      const float e2 = __expf(m2 - nm2), e3 = __expf(m3 - nm3);
      const float w0 = __expf(a0 - nm0), w1 = __expf(a1 - nm1);
      const float w2 = __expf(a2 - nm2), w3 = __expf(a3 - nm3);
      float t0 = w0, t1 = w1, t2 = w2, t3 = w3;
      #pragma unroll
      for (int msk = 32; msk; msk >>= 1) {
        t0 += __shfl_xor(t0, msk, 64);
        t1 += __shfl_xor(t1, msk, 64);
        t2 += __shfl_xor(t2, msk, 64);
        t3 += __shfl_xor(t3, msk, 64);
      }
      s0 = s0 * e0 + t0; s1 = s1 * e1 + t1;
      s2 = s2 * e2 + t2; s3 = s3 * e3 + t3;
      m0 = nm0; m1 = nm1; m2 = nm2; m3 = nm3;
      *(float4*)&sw[wid][lane][0] = make_float4(w0, w1, w2, w3);
      const float sc = (h == 0) ? e0 : (h == 1) ? e1 : (h == 2) ? e2 : e3;
      ax *= sc; ay *= sc;
    }
    __syncthreads();
    if (act) {
      const __hip_bfloat162* __restrict__ ht = (const __hip_bfloat162*)h_tail + lane;
      int j = 0;
      for (; j + 4 <= rem; j += 4) {                 // 4 gathers in flight
        const int   t0 = sti[wid][j + 0], t1 = sti[wid][j + 1];
        const int   t2 = sti[wid][j + 2], t3 = sti[wid][j + 3];
        const float w0 = sw[wid][j + 0][h], w1 = sw[wid][j + 1][h];
        const float w2 = sw[wid][j + 2][h], w3 = sw[wid][j + 3][h];
        const __hip_bfloat162 v0 = ht[(size_t)t0 * 64];
        const __hip_bfloat162 v1 = ht[(size_t)t1 * 64];
        const __hip_bfloat162 v2 = ht[(size_t)t2 * 64];
        const __hip_bfloat162 v3 = ht[(size_t)t3 * 64];
        ax += w0 * bf2f(v0.x); ay += w0 * bf2f(v0.y);
        ax += w1 * bf2f(v1.x); ay += w1 * bf2f(v1.y);
        ax += w2 * bf2f(v2.x); ay += w2 * bf2f(v2.y);
        ax += w3 * bf2f(v3.x); ay += w3 * bf2f(v3.y);
      }
      for (; j < rem; ++j) {
        const float wj = sw[wid][j][h];
        const int ti = sti[wid][j];
        const __hip_bfloat162 v = ht[(size_t)ti * 64];
        ax += wj * bf2f(v.x);
        ay += wj * bf2f(v.y);
      }
    }
    __syncthreads();
  }
  const float denom = (h == 0) ? s0 : (h == 1) ? s1 : (h == 2) ? s2 : s3;
  const float inv = denom > 0.f ? 1.f / denom : 0.f;
  float ox = ax * inv, oy = ay * inv;
  ox = ox > 0.f ? ox : expm1f(ox);
  oy = oy > 0.f ? oy : expm1f(oy);
  *(float2*)(out + (size_t)n * 128 + 2 * lane) = make_float2(ox, oy);
}

extern "C" void kernel_launch(void* const* d_in, const int* in_sizes, int n_in,
                              void* d_out, int out_size, void* d_ws, size_t ws_size,
                              hipStream_t stream) {
  const float* head = (const float*)d_in[0];
  const float* tail = (const float*)d_in[1];
  const int* elist  = (const int*)d_in[2];
  const int* etype  = (const int*)d_in[3];
  const float* W    = (const float*)d_in[4];
  const float* W_e  = (const float*)d_in[5];
  const float* a_l  = (const float*)d_in[6];
  const float* a_r  = (const float*)d_in[7];
  const float* a_e  = (const float*)d_in[8];
  const float* emb  = (const float*)d_in[9];
  const int* head_ind = elist;
  const int* tail_ind = elist + NEDGE;
  (void)in_sizes; (void)n_in; (void)out_size; (void)ws_size;

  char* p = (char*)d_ws;
  size_t o = 0;
  auto carve = [&](size_t bytes) {
    char* r = p + o;
    o += (bytes + 255) & ~(size_t)255;
    return r;
  };
  // total ~36.0 MB
  __hip_bfloat16* h_tail = (__hip_bfloat16*)carve((size_t)N_TAILN * 128 * 2);  // 25.6 MB
  int*   pt     = (int*)   carve((size_t)NEDGE * 4);                            // 6.4 MB
  float* h_l    = (float*) carve((size_t)N_HEADN * 4 * 4);                      // 1.6 MB
  float* h_r    = (float*) carve((size_t)N_TAILN * 4 * 4);                      // 1.6 MB
  int*   deg    = (int*)   carve((size_t)N_HEADN * 4);                          // 0.4 MB
  int*   off    = (int*)   carve((size_t)(N_HEADN + 1) * 4);                    // 0.4 MB
  int*   cursor = deg;                                                          // alias (safe, see scan3)
  int*   bsum   = (int*)   carve(512 * 4);
  float* wl     = (float*) carve(128 * 4 * 4);
  float* wr     = (float*) carve(128 * 4 * 4);
  float* he     = (float*) carve(8 * 4 * 4);

  hipMemsetAsync(deg, 0, N_HEADN * sizeof(int), stream);
  k0_prep<<<1, 128, 0, stream>>>(W, W_e, a_l, a_r, a_e, emb, wl, wr, he);
  k1_hlr<<<(N_HEADN * 64) / 256, 256, 0, stream>>>(head, wl, h_l, N_HEADN);
  k2_gemm<<<(N_TAILN + 63) / 64, 256, 0, stream>>>(tail, W, wr, h_tail, h_r);
  k3_count<<<NEDGE / 256, 256, 0, stream>>>(head_ind, deg);
  const int nb = (N_HEADN + 255) / 256;  // 391
  scan1<<<nb, 256, 0, stream>>>(deg, bsum);
  scan2<<<1, 512, 0, stream>>>(bsum, nb);
  scan3<<<nb, 256, 0, stream>>>(deg, bsum, off, cursor);
  k3_scatter<<<NEDGE / 256, 256, 0, stream>>>(head_ind, tail_ind, etype, cursor, pt);
  k4_agg<<<N_HEADN / 4, 256, 0, stream>>>(off, pt, h_l, h_r, he, h_tail, (float*)d_out);
}

// Round 6
// 496.516 us; speedup vs baseline: 1.2628x; 1.0995x over previous
//
#include <hip/hip_runtime.h>
#include <hip/hip_bf16.h>
#include <math.h>

#define N_HEADN 100000
#define N_TAILN 100000
#define NEDGE   1600000
#define SLOPE   0.2f

static __device__ __forceinline__ float bf2f(__hip_bfloat16 x) { return __bfloat162float(x); }

// ---------------- k0: wl[128][4], he[8][4]  (fp32 in) ----------------
__global__ void k0_prep(const float* __restrict__ W,
                        const float* __restrict__ W_e,
                        const float* __restrict__ a_l,
                        const float* __restrict__ a_e,
                        const float* __restrict__ emb,
                        float* __restrict__ wl, float* __restrict__ he) {
  const int t = threadIdx.x;  // 128 threads
  #pragma unroll
  for (int h = 0; h < 4; ++h) {
    float sl = 0.f;
    for (int d = 0; d < 32; ++d)
      sl += W[t * 128 + h * 32 + d] * a_l[h * 32 + d];
    wl[t * 4 + h] = sl;
  }
  if (t < 32) {
    const int et = t >> 2, h = t & 3;
    float acc = 0.f;
    for (int d = 0; d < 32; ++d) {
      float tmp = 0.f;
      for (int f = 0; f < 32; ++f)
        tmp += emb[et * 32 + f] * W_e[f * 128 + h * 32 + d];
      acc += a_e[h * 32 + d] * tmp;
    }
    he[et * 4 + h] = acc;
  }
}

// ---------------- k0w: W fp32 -> bf16 (16 blocks x 256, 4 elems/thread) ----------------
__global__ __launch_bounds__(256) void k0w(const float* __restrict__ W,
                                           __hip_bfloat16* __restrict__ Wb) {
  const int i = (blockIdx.x * 256 + threadIdx.x) * 4;
  const float4 v = *(const float4*)&W[i];
  union { unsigned short us[4]; uint2 u2; } pk;
  __hip_bfloat16 b0 = __float2bfloat16(v.x); pk.us[0] = *(unsigned short*)&b0;
  __hip_bfloat16 b1 = __float2bfloat16(v.y); pk.us[1] = *(unsigned short*)&b1;
  __hip_bfloat16 b2 = __float2bfloat16(v.z); pk.us[2] = *(unsigned short*)&b2;
  __hip_bfloat16 b3 = __float2bfloat16(v.w); pk.us[3] = *(unsigned short*)&b3;
  *(uint2*)&Wb[i] = pk.u2;
}

// ---------------- k1: h_l = head @ wl  (wave per node) ----------------
__global__ __launch_bounds__(256) void k1_hlr(const float* __restrict__ feat,
                                              const float* __restrict__ wv,
                                              float* __restrict__ o, int n) {
  const int gid = blockIdx.x * 256 + threadIdx.x;
  const int node = gid >> 6, lane = gid & 63;
  if (node >= n) return;
  const float* row = feat + (size_t)node * 128;
  const float x0 = row[lane];
  const float x1 = row[lane + 64];
  const float4 w0 = *(const float4*)(wv + lane * 4);
  const float4 w1 = *(const float4*)(wv + (lane + 64) * 4);
  float p0 = x0 * w0.x + x1 * w1.x;
  float p1 = x0 * w0.y + x1 * w1.y;
  float p2 = x0 * w0.z + x1 * w1.z;
  float p3 = x0 * w0.w + x1 * w1.w;
  #pragma unroll
  for (int m = 32; m; m >>= 1) {
    p0 += __shfl_xor(p0, m, 64);
    p1 += __shfl_xor(p1, m, 64);
    p2 += __shfl_xor(p2, m, 64);
    p3 += __shfl_xor(p3, m, 64);
  }
  if (lane == 0) *(float4*)(o + (size_t)node * 4) = make_float4(p0, p1, p2, p3);
}

// ---------------- k2: h_tail = tail @ W (bf16) + h_r from epilogue ----------------
// 64 rows/block. sW bf16 [k][c] 32 KB (copied from pre-converted Wb);
// sA bf16 [k][r] pad 68 (17.4 KB, keeps ds_read_b64 8B-aligned). 50 KB LDS -> 3 blocks/CU.
// Thread tile 4 rows x 8 cols. h_r[r][h] = sum_d a_r[h][d] * acc_cols(h*32+d) -- free epilogue.
__global__ __launch_bounds__(256) void k2_gemm(const float* __restrict__ A,
                                               const __hip_bfloat16* __restrict__ Wb,
                                               const float* __restrict__ a_r,
                                               __hip_bfloat16* __restrict__ out,
                                               float* __restrict__ h_r) {
  __shared__ __hip_bfloat16 sW[128 * 128];   // [k][c]
  __shared__ __hip_bfloat16 sA[128 * 68];    // [k][r]
  const int t = threadIdx.x;
  {
    const uint4* src = (const uint4*)Wb;
    uint4* dst = (uint4*)sW;
    #pragma unroll
    for (int i = 0; i < 8; ++i) dst[i * 256 + t] = src[i * 256 + t];
  }
  const int r0 = blockIdx.x * 64;
  #pragma unroll
  for (int ii = 0; ii < 8; ++ii) {
    const int i = ii * 256 + t;
    const int r = i >> 5, k4 = (i & 31) * 4;
    float4 v = make_float4(0.f, 0.f, 0.f, 0.f);
    if (r0 + r < N_TAILN) v = *(const float4*)&A[(size_t)(r0 + r) * 128 + k4];
    sA[(k4 + 0) * 68 + r] = __float2bfloat16(v.x);
    sA[(k4 + 1) * 68 + r] = __float2bfloat16(v.y);
    sA[(k4 + 2) * 68 + r] = __float2bfloat16(v.z);
    sA[(k4 + 3) * 68 + r] = __float2bfloat16(v.w);
  }
  __syncthreads();

  const int tc = t & 15, tr = t >> 4;
  const int c8 = tc * 8, r4 = tr * 4;
  float acc[4][8];
  #pragma unroll
  for (int i = 0; i < 4; ++i)
    #pragma unroll
    for (int j = 0; j < 8; ++j) acc[i][j] = 0.f;

  #pragma unroll 2
  for (int k = 0; k < 128; ++k) {
    const uint2 ab = *(const uint2*)&sA[k * 68 + r4];
    const float ar[4] = {__uint_as_float(ab.x << 16), __uint_as_float(ab.x & 0xffff0000u),
                         __uint_as_float(ab.y << 16), __uint_as_float(ab.y & 0xffff0000u)};
    const uint4 wbv = *(const uint4*)&sW[k * 128 + c8];
    float w[8];
    w[0] = __uint_as_float(wbv.x << 16); w[1] = __uint_as_float(wbv.x & 0xffff0000u);
    w[2] = __uint_as_float(wbv.y << 16); w[3] = __uint_as_float(wbv.y & 0xffff0000u);
    w[4] = __uint_as_float(wbv.z << 16); w[5] = __uint_as_float(wbv.z & 0xffff0000u);
    w[6] = __uint_as_float(wbv.w << 16); w[7] = __uint_as_float(wbv.w & 0xffff0000u);
    #pragma unroll
    for (int i = 0; i < 4; ++i)
      #pragma unroll
      for (int j = 0; j < 8; ++j)
        acc[i][j] += ar[i] * w[j];
  }

  // epilogue h_r: dot acc rows with a_r slice, reduce over the 4 tc's of this head
  const int hh = tc >> 2, d0 = (tc & 3) * 8;
  const float4 ar0 = *(const float4*)&a_r[hh * 32 + d0];
  const float4 ar1 = *(const float4*)&a_r[hh * 32 + d0 + 4];
  #pragma unroll
  for (int i = 0; i < 4; ++i) {
    float hr = acc[i][0] * ar0.x + acc[i][1] * ar0.y + acc[i][2] * ar0.z + acc[i][3] * ar0.w
             + acc[i][4] * ar1.x + acc[i][5] * ar1.y + acc[i][6] * ar1.z + acc[i][7] * ar1.w;
    hr += __shfl_xor(hr, 1, 64);
    hr += __shfl_xor(hr, 2, 64);
    if ((tc & 3) == 0 && (r0 + r4 + i) < N_TAILN)
      h_r[(size_t)(r0 + r4 + i) * 4 + hh] = hr;
  }

  #pragma unroll
  for (int i = 0; i < 4; ++i) {
    const int rr = r0 + r4 + i;
    if (rr < N_TAILN) {
      union { unsigned short us[8]; uint4 u4; } pk;
      #pragma unroll
      for (int j = 0; j < 8; ++j) {
        __hip_bfloat16 b = __float2bfloat16(acc[i][j]);
        pk.us[j] = *(unsigned short*)&b;
      }
      *(uint4*)&out[(size_t)rr * 128 + c8] = pk.u4;
    }
  }
}

// ---------------- CSR build ----------------
__global__ __launch_bounds__(256) void k3_count(const int* __restrict__ head_ind,
                                                int* __restrict__ deg) {
  const int e = blockIdx.x * 256 + threadIdx.x;
  atomicAdd(&deg[head_ind[e]], 1);
}

__global__ __launch_bounds__(256) void scan1(const int* __restrict__ deg, int* __restrict__ bsum) {
  __shared__ int sm[256];
  const int i = blockIdx.x * 256 + threadIdx.x;
  sm[threadIdx.x] = (i < N_HEADN) ? deg[i] : 0;
  __syncthreads();
  for (int st = 128; st > 0; st >>= 1) {
    if (threadIdx.x < st) sm[threadIdx.x] += sm[threadIdx.x + st];
    __syncthreads();
  }
  if (threadIdx.x == 0) bsum[blockIdx.x] = sm[0];
}

__global__ __launch_bounds__(512) void scan2(int* __restrict__ bsum, int nb) {
  __shared__ int sm[512];
  const int t = threadIdx.x;
  const int v = (t < nb) ? bsum[t] : 0;
  sm[t] = v;
  __syncthreads();
  for (int st = 1; st < 512; st <<= 1) {
    const int add = (t >= st) ? sm[t - st] : 0;
    __syncthreads();
    sm[t] += add;
    __syncthreads();
  }
  if (t < nb) bsum[t] = sm[t] - v;  // exclusive
}

// cursor aliases deg: each thread reads deg[i] before writing cursor[i].
__global__ __launch_bounds__(256) void scan3(const int* __restrict__ deg,
                                             const int* __restrict__ bsum,
                                             int* __restrict__ off, int* __restrict__ cursor) {
  __shared__ int sm[256];
  const int i = blockIdx.x * 256 + threadIdx.x;
  const int v = (i < N_HEADN) ? deg[i] : 0;
  sm[threadIdx.x] = v;
  __syncthreads();
  for (int st = 1; st < 256; st <<= 1) {
    const int add = (threadIdx.x >= st) ? sm[threadIdx.x - st] : 0;
    __syncthreads();
    sm[threadIdx.x] += add;
    __syncthreads();
  }
  const int excl = sm[threadIdx.x] - v + bsum[blockIdx.x];
  if (i < N_HEADN) { off[i] = excl; cursor[i] = excl; }
  if (i == N_HEADN - 1) off[N_HEADN] = excl + v;
}

// pt slot = ti | (etype << 17)   (ti < 2^17, etype < 8)
__global__ __launch_bounds__(256) void k3_scatter(const int* __restrict__ head_ind,
                                                  const int* __restrict__ tail_ind,
                                                  const int* __restrict__ etype,
                                                  int* __restrict__ cursor,
                                                  int* __restrict__ pt) {
  const int e = blockIdx.x * 256 + threadIdx.x;
  const int hi = head_ind[e];
  const int ppos = atomicAdd(&cursor[hi], 1);
  pt[ppos] = tail_ind[e] | (etype[e] << 17);
}

// ---------------- k4: per-node online softmax + aggregation (barrier-free waves) ----------------
__global__ __launch_bounds__(256) void k4_agg(const int* __restrict__ off,
                                              const int* __restrict__ pt,
                                              const float* __restrict__ h_l,
                                              const float* __restrict__ h_r,
                                              const float* __restrict__ he,
                                              const __hip_bfloat16* __restrict__ h_tail,
                                              float* __restrict__ out) {
  __shared__ __align__(16) float sw[4][64][4];
  __shared__ int sti[4][64];
  __shared__ float she[32];
  const int wid = threadIdx.x >> 6;
  const int lane = threadIdx.x & 63;
  if (threadIdx.x < 32) she[threadIdx.x] = he[threadIdx.x];
  __syncthreads();                                  // only barrier: she visibility
  const int n = blockIdx.x * 4 + wid;               // grid exact: 25000*4
  const int s = off[n], e = off[n + 1];
  const int nch = (e - s + 63) >> 6;
  const float4 hl = *(const float4*)(h_l + (size_t)n * 4);
  const int h = lane >> 4;                          // head owning dims 2*lane, 2*lane+1
  float m0 = -1e30f, m1 = -1e30f, m2 = -1e30f, m3 = -1e30f;
  float s0 = 0.f, s1 = 0.f, s2 = 0.f, s3 = 0.f;
  float ax = 0.f, ay = 0.f;
  for (int c = 0; c < nch; ++c) {                   // waves fully independent
    const int base = s + (c << 6);
    const int rem = min(64, e - base);
    float a0 = -1e30f, a1 = -1e30f, a2 = -1e30f, a3 = -1e30f;
    if (lane < rem) {
      const int pk = pt[base + lane];
      const int ti = pk & 0x1FFFF;
      const int et = pk >> 17;
      const float4 hr = *(const float4*)(h_r + (size_t)ti * 4);
      a0 = hl.x + hr.x + she[et * 4 + 0];
      a1 = hl.y + hr.y + she[et * 4 + 1];
      a2 = hl.z + hr.z + she[et * 4 + 2];
      a3 = hl.w + hr.w + she[et * 4 + 3];
      a0 = a0 > 0.f ? a0 : SLOPE * a0;
      a1 = a1 > 0.f ? a1 : SLOPE * a1;
      a2 = a2 > 0.f ? a2 : SLOPE * a2;
      a3 = a3 > 0.f ? a3 : SLOPE * a3;
      sti[wid][lane] = ti;
    }
    float c0 = a0, c1 = a1, c2 = a2, c3 = a3;
    #pragma unroll
    for (int msk = 32; msk; msk >>= 1) {
      c0 = fmaxf(c0, __shfl_xor(c0, msk, 64));
      c1 = fmaxf(c1, __shfl_xor(c1, msk, 64));
      c2 = fmaxf(c2, __shfl_xor(c2, msk, 64));
      c3 = fmaxf(c3, __shfl_xor(c3, msk, 64));
    }
    const float nm0 = fmaxf(m0, c0), nm1 = fmaxf(m1, c1);
    const float nm2 = fmaxf(m2, c2), nm3 = fmaxf(m3, c3);
    const float e0 = __expf(m0 - nm0), e1 = __expf(m1 - nm1);
    const float e2 = __expf(m2 - nm2), e3 = __expf(m3 - nm3);
    const float w0 = __expf(a0 - nm0), w1 = __expf(a1 - nm1);
    const float w2 = __expf(a2 - nm2), w3 = __expf(a3 - nm3);
    float t0 = w0, t1 = w1, t2 = w2, t3 = w3;
    #pragma unroll
    for (int msk = 32; msk; msk >>= 1) {
      t0 += __shfl_xor(t0, msk, 64);
      t1 += __shfl_xor(t1, msk, 64);
      t2 += __shfl_xor(t2, msk, 64);
      t3 += __shfl_xor(t3, msk, 64);
    }
    s0 = s0 * e0 + t0; s1 = s1 * e1 + t1;
    s2 = s2 * e2 + t2; s3 = s3 * e3 + t3;
    m0 = nm0; m1 = nm1; m2 = nm2; m3 = nm3;
    *(float4*)&sw[wid][lane][0] = make_float4(w0, w1, w2, w3);
    const float sc = (h == 0) ? e0 : (h == 1) ? e1 : (h == 2) ? e2 : e3;
    ax *= sc; ay *= sc;
    __builtin_amdgcn_wave_barrier();                // order LDS write phase vs read phase
    {
      const __hip_bfloat162* __restrict__ ht = (const __hip_bfloat162*)h_tail + lane;
      int j = 0;
      for (; j + 4 <= rem; j += 4) {                // 4 gathers in flight
        const int   t0i = sti[wid][j + 0], t1i = sti[wid][j + 1];
        const int   t2i = sti[wid][j + 2], t3i = sti[wid][j + 3];
        const float q0 = sw[wid][j + 0][h], q1 = sw[wid][j + 1][h];
        const float q2 = sw[wid][j + 2][h], q3 = sw[wid][j + 3][h];
        const __hip_bfloat162 v0 = ht[(size_t)t0i * 64];
        const __hip_bfloat162 v1 = ht[(size_t)t1i * 64];
        const __hip_bfloat162 v2 = ht[(size_t)t2i * 64];
        const __hip_bfloat162 v3 = ht[(size_t)t3i * 64];
        ax += q0 * bf2f(v0.x); ay += q0 * bf2f(v0.y);
        ax += q1 * bf2f(v1.x); ay += q1 * bf2f(v1.y);
        ax += q2 * bf2f(v2.x); ay += q2 * bf2f(v2.y);
        ax += q3 * bf2f(v3.x); ay += q3 * bf2f(v3.y);
      }
      for (; j < rem; ++j) {
        const float qj = sw[wid][j][h];
        const int ti = sti[wid][j];
        const __hip_bfloat162 v = ht[(size_t)ti * 64];
        ax += qj * bf2f(v.x);
        ay += qj * bf2f(v.y);
      }
    }
    __builtin_amdgcn_wave_barrier();                // don't hoist next chunk's writes above reads
  }
  const float denom = (h == 0) ? s0 : (h == 1) ? s1 : (h == 2) ? s2 : s3;
  const float inv = denom > 0.f ? 1.f / denom : 0.f;
  float ox = ax * inv, oy = ay * inv;
  ox = ox > 0.f ? ox : expm1f(ox);
  oy = oy > 0.f ? oy : expm1f(oy);
  *(float2*)(out + (size_t)n * 128 + 2 * lane) = make_float2(ox, oy);
}

extern "C" void kernel_launch(void* const* d_in, const int* in_sizes, int n_in,
                              void* d_out, int out_size, void* d_ws, size_t ws_size,
                              hipStream_t stream) {
  const float* head = (const float*)d_in[0];
  const float* tail = (const float*)d_in[1];
  const int* elist  = (const int*)d_in[2];
  const int* etype  = (const int*)d_in[3];
  const float* W    = (const float*)d_in[4];
  const float* W_e  = (const float*)d_in[5];
  const float* a_l  = (const float*)d_in[6];
  const float* a_r  = (const float*)d_in[7];
  const float* a_e  = (const float*)d_in[8];
  const float* emb  = (const float*)d_in[9];
  const int* head_ind = elist;
  const int* tail_ind = elist + NEDGE;
  (void)in_sizes; (void)n_in; (void)out_size; (void)ws_size;

  char* p = (char*)d_ws;
  size_t o = 0;
  auto carve = [&](size_t bytes) {
    char* r = p + o;
    o += (bytes + 255) & ~(size_t)255;
    return r;
  };
  // total ~36.1 MB (known-good footprint)
  __hip_bfloat16* h_tail = (__hip_bfloat16*)carve((size_t)N_TAILN * 128 * 2);  // 25.6 MB
  int*   pt     = (int*)   carve((size_t)NEDGE * 4);                            // 6.4 MB
  float* h_l    = (float*) carve((size_t)N_HEADN * 4 * 4);                      // 1.6 MB
  float* h_r    = (float*) carve((size_t)N_TAILN * 4 * 4);                      // 1.6 MB
  int*   deg    = (int*)   carve((size_t)N_HEADN * 4);                          // 0.4 MB
  int*   off    = (int*)   carve((size_t)(N_HEADN + 1) * 4);                    // 0.4 MB
  int*   cursor = deg;                                                          // alias (safe, see scan3)
  int*   bsum   = (int*)   carve(512 * 4);
  float* wl     = (float*) carve(128 * 4 * 4);
  float* he     = (float*) carve(8 * 4 * 4);
  __hip_bfloat16* Wb = (__hip_bfloat16*)carve(16384 * 2);                       // 32 KB

  hipMemsetAsync(deg, 0, N_HEADN * sizeof(int), stream);
  k0_prep<<<1, 128, 0, stream>>>(W, W_e, a_l, a_e, emb, wl, he);
  k0w<<<16, 256, 0, stream>>>(W, Wb);
  k1_hlr<<<(N_HEADN * 64) / 256, 256, 0, stream>>>(head, wl, h_l, N_HEADN);
  k2_gemm<<<(N_TAILN + 63) / 64, 256, 0, stream>>>(tail, Wb, a_r, h_tail, h_r);
  k3_count<<<NEDGE / 256, 256, 0, stream>>>(head_ind, deg);
  const int nb = (N_HEADN + 255) / 256;  // 391
  scan1<<<nb, 256, 0, stream>>>(deg, bsum);
  scan2<<<1, 512, 0, stream>>>(bsum, nb);
  scan3<<<nb, 256, 0, stream>>>(deg, bsum, off, cursor);
  k3_scatter<<<NEDGE / 256, 256, 0, stream>>>(head_ind, tail_ind, etype, cursor, pt);
  k4_agg<<<N_HEADN / 4, 256, 0, stream>>>(off, pt, h_l, h_r, he, h_tail, (float*)d_out);
}

// Round 7
// 383.398 us; speedup vs baseline: 1.6354x; 1.2950x over previous
//
#include <hip/hip_runtime.h>
#include <hip/hip_bf16.h>
#include <math.h>

#define N_HEADN 100000
#define N_TAILN 100000
#define NEDGE   1600000
#define SLOPE   0.2f

#define NB   196      // buckets: head>>9
#define HPB  512      // heads per bucket
#define BCAP 9216     // bucket capacity (mean 8191, sigma ~90; 9216 = +11 sigma)

static __device__ __forceinline__ float bf2f(__hip_bfloat16 x) { return __bfloat162float(x); }

// ---------------- k0: wl[128][4], he[8][4]  (fp32 in) ----------------
__global__ void k0_prep(const float* __restrict__ W,
                        const float* __restrict__ W_e,
                        const float* __restrict__ a_l,
                        const float* __restrict__ a_e,
                        const float* __restrict__ emb,
                        float* __restrict__ wl, float* __restrict__ he) {
  const int t = threadIdx.x;  // 128 threads
  #pragma unroll
  for (int h = 0; h < 4; ++h) {
    float sl = 0.f;
    for (int d = 0; d < 32; ++d)
      sl += W[t * 128 + h * 32 + d] * a_l[h * 32 + d];
    wl[t * 4 + h] = sl;
  }
  if (t < 32) {
    const int et = t >> 2, h = t & 3;
    float acc = 0.f;
    for (int d = 0; d < 32; ++d) {
      float tmp = 0.f;
      for (int f = 0; f < 32; ++f)
        tmp += emb[et * 32 + f] * W_e[f * 128 + h * 32 + d];
      acc += a_e[h * 32 + d] * tmp;
    }
    he[et * 4 + h] = acc;
  }
}

// ---------------- k0w: W fp32 -> bf16 ----------------
__global__ __launch_bounds__(256) void k0w(const float* __restrict__ W,
                                           __hip_bfloat16* __restrict__ Wb) {
  const int i = (blockIdx.x * 256 + threadIdx.x) * 4;
  const float4 v = *(const float4*)&W[i];
  union { unsigned short us[4]; uint2 u2; } pk;
  __hip_bfloat16 b0 = __float2bfloat16(v.x); pk.us[0] = *(unsigned short*)&b0;
  __hip_bfloat16 b1 = __float2bfloat16(v.y); pk.us[1] = *(unsigned short*)&b1;
  __hip_bfloat16 b2 = __float2bfloat16(v.z); pk.us[2] = *(unsigned short*)&b2;
  __hip_bfloat16 b3 = __float2bfloat16(v.w); pk.us[3] = *(unsigned short*)&b3;
  *(uint2*)&Wb[i] = pk.u2;
}

// ---------------- k1: h_l = head @ wl  (wave per node) ----------------
__global__ __launch_bounds__(256) void k1_hlr(const float* __restrict__ feat,
                                              const float* __restrict__ wv,
                                              float* __restrict__ o, int n) {
  const int gid = blockIdx.x * 256 + threadIdx.x;
  const int node = gid >> 6, lane = gid & 63;
  if (node >= n) return;
  const float* row = feat + (size_t)node * 128;
  const float x0 = row[lane];
  const float x1 = row[lane + 64];
  const float4 w0 = *(const float4*)(wv + lane * 4);
  const float4 w1 = *(const float4*)(wv + (lane + 64) * 4);
  float p0 = x0 * w0.x + x1 * w1.x;
  float p1 = x0 * w0.y + x1 * w1.y;
  float p2 = x0 * w0.z + x1 * w1.z;
  float p3 = x0 * w0.w + x1 * w1.w;
  #pragma unroll
  for (int m = 32; m; m >>= 1) {
    p0 += __shfl_xor(p0, m, 64);
    p1 += __shfl_xor(p1, m, 64);
    p2 += __shfl_xor(p2, m, 64);
    p3 += __shfl_xor(p3, m, 64);
  }
  if (lane == 0) *(float4*)(o + (size_t)node * 4) = make_float4(p0, p1, p2, p3);
}

// ---------------- k2: h_tail = tail @ W (bf16) + h_r from epilogue ----------------
__global__ __launch_bounds__(256) void k2_gemm(const float* __restrict__ A,
                                               const __hip_bfloat16* __restrict__ Wb,
                                               const float* __restrict__ a_r,
                                               __hip_bfloat16* __restrict__ out,
                                               float* __restrict__ h_r) {
  __shared__ __hip_bfloat16 sW[128 * 128];   // [k][c]
  __shared__ __hip_bfloat16 sA[128 * 68];    // [k][r]
  const int t = threadIdx.x;
  {
    const uint4* src = (const uint4*)Wb;
    uint4* dst = (uint4*)sW;
    #pragma unroll
    for (int i = 0; i < 8; ++i) dst[i * 256 + t] = src[i * 256 + t];
  }
  const int r0 = blockIdx.x * 64;
  #pragma unroll
  for (int ii = 0; ii < 8; ++ii) {
    const int i = ii * 256 + t;
    const int r = i >> 5, k4 = (i & 31) * 4;
    float4 v = make_float4(0.f, 0.f, 0.f, 0.f);
    if (r0 + r < N_TAILN) v = *(const float4*)&A[(size_t)(r0 + r) * 128 + k4];
    sA[(k4 + 0) * 68 + r] = __float2bfloat16(v.x);
    sA[(k4 + 1) * 68 + r] = __float2bfloat16(v.y);
    sA[(k4 + 2) * 68 + r] = __float2bfloat16(v.z);
    sA[(k4 + 3) * 68 + r] = __float2bfloat16(v.w);
  }
  __syncthreads();

  const int tc = t & 15, tr = t >> 4;
  const int c8 = tc * 8, r4 = tr * 4;
  float acc[4][8];
  #pragma unroll
  for (int i = 0; i < 4; ++i)
    #pragma unroll
    for (int j = 0; j < 8; ++j) acc[i][j] = 0.f;

  #pragma unroll 2
  for (int k = 0; k < 128; ++k) {
    const uint2 ab = *(const uint2*)&sA[k * 68 + r4];
    const float ar[4] = {__uint_as_float(ab.x << 16), __uint_as_float(ab.x & 0xffff0000u),
                         __uint_as_float(ab.y << 16), __uint_as_float(ab.y & 0xffff0000u)};
    const uint4 wbv = *(const uint4*)&sW[k * 128 + c8];
    float w[8];
    w[0] = __uint_as_float(wbv.x << 16); w[1] = __uint_as_float(wbv.x & 0xffff0000u);
    w[2] = __uint_as_float(wbv.y << 16); w[3] = __uint_as_float(wbv.y & 0xffff0000u);
    w[4] = __uint_as_float(wbv.z << 16); w[5] = __uint_as_float(wbv.z & 0xffff0000u);
    w[6] = __uint_as_float(wbv.w << 16); w[7] = __uint_as_float(wbv.w & 0xffff0000u);
    #pragma unroll
    for (int i = 0; i < 4; ++i)
      #pragma unroll
      for (int j = 0; j < 8; ++j)
        acc[i][j] += ar[i] * w[j];
  }

  // epilogue h_r: dot acc rows with a_r slice, reduce over the 4 tc's of this head
  const int hh = tc >> 2, d0 = (tc & 3) * 8;
  const float4 ar0 = *(const float4*)&a_r[hh * 32 + d0];
  const float4 ar1 = *(const float4*)&a_r[hh * 32 + d0 + 4];
  #pragma unroll
  for (int i = 0; i < 4; ++i) {
    float hr = acc[i][0] * ar0.x + acc[i][1] * ar0.y + acc[i][2] * ar0.z + acc[i][3] * ar0.w
             + acc[i][4] * ar1.x + acc[i][5] * ar1.y + acc[i][6] * ar1.z + acc[i][7] * ar1.w;
    hr += __shfl_xor(hr, 1, 64);
    hr += __shfl_xor(hr, 2, 64);
    if ((tc & 3) == 0 && (r0 + r4 + i) < N_TAILN)
      h_r[(size_t)(r0 + r4 + i) * 4 + hh] = hr;
  }

  #pragma unroll
  for (int i = 0; i < 4; ++i) {
    const int rr = r0 + r4 + i;
    if (rr < N_TAILN) {
      union { unsigned short us[8]; uint4 u4; } pk;
      #pragma unroll
      for (int j = 0; j < 8; ++j) {
        __hip_bfloat16 b = __float2bfloat16(acc[i][j]);
        pk.us[j] = *(unsigned short*)&b;
      }
      *(uint4*)&out[(size_t)rr * 128 + c8] = pk.u4;
    }
  }
}

// ---------------- p1: partition edges into 196 head-buckets (4B records) ----------------
// record = ti | et<<17 | hlocal<<20   (ti<2^17, et<8, hlocal<512)
__global__ __launch_bounds__(256) void p1_part(const int* __restrict__ head_ind,
                                               const int* __restrict__ tail_ind,
                                               const int* __restrict__ etype,
                                               int* __restrict__ bucketCursor,
                                               unsigned int* __restrict__ recs) {
  __shared__ int hist[NB];
  const int t = threadIdx.x;
  for (int i = t; i < NB; i += 256) hist[i] = 0;
  __syncthreads();
  const int e0 = blockIdx.x * 6400;                  // 250 blocks x 6400 = 1.6M
  int h[25];
  #pragma unroll
  for (int i = 0; i < 25; ++i) {
    h[i] = head_ind[e0 + i * 256 + t];
    atomicAdd(&hist[h[i] >> 9], 1);
  }
  __syncthreads();
  for (int i = t; i < NB; i += 256) {
    const int c = hist[i];
    hist[i] = atomicAdd(&bucketCursor[i], c);        // hist becomes running cursor
  }
  __syncthreads();
  #pragma unroll
  for (int i = 0; i < 25; ++i) {
    const int e = e0 + i * 256 + t;
    const int hi = h[i];
    const int b = hi >> 9;
    const int pos = atomicAdd(&hist[b], 1);
    recs[b * BCAP + pos] = (unsigned)tail_ind[e] | ((unsigned)etype[e] << 17)
                         | ((unsigned)(hi & 511) << 20);
  }
}

// ---------------- p2: per-head degree from bucket records (LDS hist, no global atomics) ----
__global__ __launch_bounds__(256) void p2_count(const unsigned int* __restrict__ recs,
                                                const int* __restrict__ bucketCursor,
                                                int* __restrict__ deg) {
  __shared__ int hist[HPB];
  const int b = blockIdx.x, t = threadIdx.x;
  for (int i = t; i < HPB; i += 256) hist[i] = 0;
  __syncthreads();
  const int cnt = bucketCursor[b];
  for (int i = t; i < cnt; i += 256)
    atomicAdd(&hist[recs[b * BCAP + i] >> 20], 1);
  __syncthreads();
  const int h0 = b * HPB;
  for (int i = t; i < HPB; i += 256)
    if (h0 + i < N_HEADN) deg[h0 + i] = hist[i];
}

// ---------------- scans ----------------
__global__ __launch_bounds__(256) void scan1(const int* __restrict__ deg, int* __restrict__ bsum) {
  __shared__ int sm[256];
  const int i = blockIdx.x * 256 + threadIdx.x;
  sm[threadIdx.x] = (i < N_HEADN) ? deg[i] : 0;
  __syncthreads();
  for (int st = 128; st > 0; st >>= 1) {
    if (threadIdx.x < st) sm[threadIdx.x] += sm[threadIdx.x + st];
    __syncthreads();
  }
  if (threadIdx.x == 0) bsum[blockIdx.x] = sm[0];
}

__global__ __launch_bounds__(512) void scan2(int* __restrict__ bsum, int nb) {
  __shared__ int sm[512];
  const int t = threadIdx.x;
  const int v = (t < nb) ? bsum[t] : 0;
  sm[t] = v;
  __syncthreads();
  for (int st = 1; st < 512; st <<= 1) {
    const int add = (t >= st) ? sm[t - st] : 0;
    __syncthreads();
    sm[t] += add;
    __syncthreads();
  }
  if (t < nb) bsum[t] = sm[t] - v;  // exclusive
}

__global__ __launch_bounds__(256) void scan3(const int* __restrict__ deg,
                                             const int* __restrict__ bsum,
                                             int* __restrict__ off) {
  __shared__ int sm[256];
  const int i = blockIdx.x * 256 + threadIdx.x;
  const int v = (i < N_HEADN) ? deg[i] : 0;
  sm[threadIdx.x] = v;
  __syncthreads();
  for (int st = 1; st < 256; st <<= 1) {
    const int add = (threadIdx.x >= st) ? sm[threadIdx.x - st] : 0;
    __syncthreads();
    sm[threadIdx.x] += add;
    __syncthreads();
  }
  const int excl = sm[threadIdx.x] - v + bsum[blockIdx.x];
  if (i < N_HEADN) off[i] = excl;
  if (i == N_HEADN - 1) off[N_HEADN] = excl + v;
}

// ---------------- p3: bucket -> CSR scatter with LDS cursors (L2-local pt writes) -------
__global__ __launch_bounds__(256) void p3_scatter(const unsigned int* __restrict__ recs,
                                                  const int* __restrict__ bucketCursor,
                                                  const int* __restrict__ off,
                                                  int* __restrict__ pt) {
  __shared__ int cur[HPB];
  const int b = blockIdx.x, t = threadIdx.x;
  const int h0 = b * HPB;
  for (int i = t; i < HPB; i += 256)
    cur[i] = (h0 + i < N_HEADN) ? off[h0 + i] : 0;
  __syncthreads();
  const int cnt = bucketCursor[b];
  for (int i = t; i < cnt; i += 256) {
    const unsigned r = recs[b * BCAP + i];
    const int pos = atomicAdd(&cur[r >> 20], 1);
    pt[pos] = (int)(r & 0xFFFFFu);                   // ti | et<<17
  }
}

// ---------------- k4: per-node online softmax + aggregation (barrier-free waves) --------
__global__ __launch_bounds__(256) void k4_agg(const int* __restrict__ off,
                                              const int* __restrict__ pt,
                                              const float* __restrict__ h_l,
                                              const float* __restrict__ h_r,
                                              const float* __restrict__ he,
                                              const __hip_bfloat16* __restrict__ h_tail,
                                              float* __restrict__ out) {
  __shared__ __align__(16) float sw[4][64][4];
  __shared__ int sti[4][64];
  __shared__ float she[32];
  const int wid = threadIdx.x >> 6;
  const int lane = threadIdx.x & 63;
  if (threadIdx.x < 32) she[threadIdx.x] = he[threadIdx.x];
  __syncthreads();                                  // only barrier: she visibility
  const int n = blockIdx.x * 4 + wid;               // grid exact: 25000*4
  const int s = off[n], e = off[n + 1];
  const int nch = (e - s + 63) >> 6;
  const float4 hl = *(const float4*)(h_l + (size_t)n * 4);
  const int h = lane >> 4;                          // head owning dims 2*lane, 2*lane+1
  float m0 = -1e30f, m1 = -1e30f, m2 = -1e30f, m3 = -1e30f;
  float s0 = 0.f, s1 = 0.f, s2 = 0.f, s3 = 0.f;
  float ax = 0.f, ay = 0.f;
  for (int c = 0; c < nch; ++c) {                   // waves fully independent
    const int base = s + (c << 6);
    const int rem = min(64, e - base);
    float a0 = -1e30f, a1 = -1e30f, a2 = -1e30f, a3 = -1e30f;
    if (lane < rem) {
      const int pk = pt[base + lane];
      const int ti = pk & 0x1FFFF;
      const int et = pk >> 17;
      const float4 hr = *(const float4*)(h_r + (size_t)ti * 4);
      a0 = hl.x + hr.x + she[et * 4 + 0];
      a1 = hl.y + hr.y + she[et * 4 + 1];
      a2 = hl.z + hr.z + she[et * 4 + 2];
      a3 = hl.w + hr.w + she[et * 4 + 3];
      a0 = a0 > 0.f ? a0 : SLOPE * a0;
      a1 = a1 > 0.f ? a1 : SLOPE * a1;
      a2 = a2 > 0.f ? a2 : SLOPE * a2;
      a3 = a3 > 0.f ? a3 : SLOPE * a3;
      sti[wid][lane] = ti;
    }
    float c0 = a0, c1 = a1, c2 = a2, c3 = a3;
    #pragma unroll
    for (int msk = 32; msk; msk >>= 1) {
      c0 = fmaxf(c0, __shfl_xor(c0, msk, 64));
      c1 = fmaxf(c1, __shfl_xor(c1, msk, 64));
      c2 = fmaxf(c2, __shfl_xor(c2, msk, 64));
      c3 = fmaxf(c3, __shfl_xor(c3, msk, 64));
    }
    const float nm0 = fmaxf(m0, c0), nm1 = fmaxf(m1, c1);
    const float nm2 = fmaxf(m2, c2), nm3 = fmaxf(m3, c3);
    const float e0 = __expf(m0 - nm0), e1 = __expf(m1 - nm1);
    const float e2 = __expf(m2 - nm2), e3 = __expf(m3 - nm3);
    const float w0 = __expf(a0 - nm0), w1 = __expf(a1 - nm1);
    const float w2 = __expf(a2 - nm2), w3 = __expf(a3 - nm3);
    float t0 = w0, t1 = w1, t2 = w2, t3 = w3;
    #pragma unroll
    for (int msk = 32; msk; msk >>= 1) {
      t0 += __shfl_xor(t0, msk, 64);
      t1 += __shfl_xor(t1, msk, 64);
      t2 += __shfl_xor(t2, msk, 64);
      t3 += __shfl_xor(t3, msk, 64);
    }
    s0 = s0 * e0 + t0; s1 = s1 * e1 + t1;
    s2 = s2 * e2 + t2; s3 = s3 * e3 + t3;
    m0 = nm0; m1 = nm1; m2 = nm2; m3 = nm3;
    *(float4*)&sw[wid][lane][0] = make_float4(w0, w1, w2, w3);
    const float sc = (h == 0) ? e0 : (h == 1) ? e1 : (h == 2) ? e2 : e3;
    ax *= sc; ay *= sc;
    __builtin_amdgcn_wave_barrier();
    {
      const __hip_bfloat162* __restrict__ ht = (const __hip_bfloat162*)h_tail + lane;
      int j = 0;
      for (; j + 4 <= rem; j += 4) {
        const int   t0i = sti[wid][j + 0], t1i = sti[wid][j + 1];
        const int   t2i = sti[wid][j + 2], t3i = sti[wid][j + 3];
        const float q0 = sw[wid][j + 0][h], q1 = sw[wid][j + 1][h];
        const float q2 = sw[wid][j + 2][h], q3 = sw[wid][j + 3][h];
        const __hip_bfloat162 v0 = ht[(size_t)t0i * 64];
        const __hip_bfloat162 v1 = ht[(size_t)t1i * 64];
        const __hip_bfloat162 v2 = ht[(size_t)t2i * 64];
        const __hip_bfloat162 v3 = ht[(size_t)t3i * 64];
        ax += q0 * bf2f(v0.x); ay += q0 * bf2f(v0.y);
        ax += q1 * bf2f(v1.x); ay += q1 * bf2f(v1.y);
        ax += q2 * bf2f(v2.x); ay += q2 * bf2f(v2.y);
        ax += q3 * bf2f(v3.x); ay += q3 * bf2f(v3.y);
      }
      for (; j < rem; ++j) {
        const float qj = sw[wid][j][h];
        const int ti = sti[wid][j];
        const __hip_bfloat162 v = ht[(size_t)ti * 64];
        ax += qj * bf2f(v.x);
        ay += qj * bf2f(v.y);
      }
    }
    __builtin_amdgcn_wave_barrier();
  }
  const float denom = (h == 0) ? s0 : (h == 1) ? s1 : (h == 2) ? s2 : s3;
  const float inv = denom > 0.f ? 1.f / denom : 0.f;
  float ox = ax * inv, oy = ay * inv;
  ox = ox > 0.f ? ox : expm1f(ox);
  oy = oy > 0.f ? oy : expm1f(oy);
  *(float2*)(out + (size_t)n * 128 + 2 * lane) = make_float2(ox, oy);
}

extern "C" void kernel_launch(void* const* d_in, const int* in_sizes, int n_in,
                              void* d_out, int out_size, void* d_ws, size_t ws_size,
                              hipStream_t stream) {
  const float* head = (const float*)d_in[0];
  const float* tail = (const float*)d_in[1];
  const int* elist  = (const int*)d_in[2];
  const int* etype  = (const int*)d_in[3];
  const float* W    = (const float*)d_in[4];
  const float* W_e  = (const float*)d_in[5];
  const float* a_l  = (const float*)d_in[6];
  const float* a_r  = (const float*)d_in[7];
  const float* a_e  = (const float*)d_in[8];
  const float* emb  = (const float*)d_in[9];
  const int* head_ind = elist;
  const int* tail_ind = elist + NEDGE;
  (void)in_sizes; (void)n_in; (void)out_size; (void)ws_size;

  char* p = (char*)d_ws;
  size_t o = 0;
  auto carve = [&](size_t bytes) {
    char* r = p + o;
    o += (bytes + 255) & ~(size_t)255;
    return r;
  };
  // total ~43.4 MB
  __hip_bfloat16* h_tail = (__hip_bfloat16*)carve((size_t)N_TAILN * 128 * 2);  // 25.6 MB
  int*   pt     = (int*)   carve((size_t)NEDGE * 4);                            // 6.4 MB
  unsigned int* recs = (unsigned int*)carve((size_t)NB * BCAP * 4);             // 7.2 MB
  float* h_l    = (float*) carve((size_t)N_HEADN * 4 * 4);                      // 1.6 MB
  float* h_r    = (float*) carve((size_t)N_TAILN * 4 * 4);                      // 1.6 MB
  int*   deg    = (int*)   carve((size_t)N_HEADN * 4);                          // 0.4 MB
  int*   off    = (int*)   carve((size_t)(N_HEADN + 1) * 4);                    // 0.4 MB
  int*   bucketCursor = (int*)carve(NB * 4);
  int*   bsum   = (int*)   carve(512 * 4);
  float* wl     = (float*) carve(128 * 4 * 4);
  float* he     = (float*) carve(8 * 4 * 4);
  __hip_bfloat16* Wb = (__hip_bfloat16*)carve(16384 * 2);                       // 32 KB

  hipMemsetAsync(bucketCursor, 0, NB * sizeof(int), stream);
  k0_prep<<<1, 128, 0, stream>>>(W, W_e, a_l, a_e, emb, wl, he);
  k0w<<<16, 256, 0, stream>>>(W, Wb);
  k1_hlr<<<(N_HEADN * 64) / 256, 256, 0, stream>>>(head, wl, h_l, N_HEADN);
  k2_gemm<<<(N_TAILN + 63) / 64, 256, 0, stream>>>(tail, Wb, a_r, h_tail, h_r);
  p1_part<<<NEDGE / 6400, 256, 0, stream>>>(head_ind, tail_ind, etype, bucketCursor, recs);
  p2_count<<<NB, 256, 0, stream>>>(recs, bucketCursor, deg);
  const int nb = (N_HEADN + 255) / 256;  // 391
  scan1<<<nb, 256, 0, stream>>>(deg, bsum);
  scan2<<<1, 512, 0, stream>>>(bsum, nb);
  scan3<<<nb, 256, 0, stream>>>(deg, bsum, off);
  p3_scatter<<<NB, 256, 0, stream>>>(recs, bucketCursor, off, pt);
  k4_agg<<<N_HEADN / 4, 256, 0, stream>>>(off, pt, h_l, h_r, he, h_tail, (float*)d_out);
}